// Round 2
// baseline (3508.157 us; speedup 1.0000x reference)
//
#include <hip/hip_runtime.h>
#include <stdint.h>

#define NN 50000
#define NE 500000

typedef short bf16x8 __attribute__((ext_vector_type(8)));
typedef float f32x4 __attribute__((ext_vector_type(4)));
typedef unsigned short u16;
typedef unsigned short u16x4 __attribute__((ext_vector_type(4)));
typedef unsigned int u32x4 __attribute__((ext_vector_type(4)));

// fp32 -> bf16 round-to-nearest-even
__device__ __forceinline__ u16 f2b(float x) {
  uint32_t u = __builtin_bit_cast(uint32_t, x);
  return (u16)((u + 0x7fffu + ((u >> 16) & 1u)) >> 16);
}
__device__ __forceinline__ float b2f(uint32_t lo16) {
  return __builtin_bit_cast(float, lo16 << 16);
}

// JAX threefry2x32, key = jax.random.key(42) -> (0, 42)
__device__ __forceinline__ void threefry(uint32_t x0, uint32_t x1,
                                         uint32_t& o0, uint32_t& o1) {
  const uint32_t k0 = 0u, k1 = 42u, k2 = 0u ^ 42u ^ 0x1BD11BDAu;
  x0 += k0; x1 += k1;
#define TFR(r) { x0 += x1; x1 = (x1 << r) | (x1 >> (32 - r)); x1 ^= x0; }
  TFR(13) TFR(15) TFR(26) TFR(6)
  x0 += k1; x1 += k2 + 1u;
  TFR(17) TFR(29) TFR(16) TFR(24)
  x0 += k2; x1 += k0 + 2u;
  TFR(13) TFR(15) TFR(26) TFR(6)
  x0 += k0; x1 += k1 + 3u;
  TFR(17) TFR(29) TFR(16) TFR(24)
  x0 += k1; x1 += k2 + 4u;
  TFR(13) TFR(15) TFR(26) TFR(6)
  x0 += k2; x1 += k0 + 5u;
#undef TFR
  o0 = x0; o1 = x1;
}

// JAX partitionable random_bits (threefry_partitionable=True, default >=0.4.30):
// per-element 64b counter j: (o0,o1)=threefry(hi32(j)=0, lo32(j)=j); bits=o0^o1.
__device__ __forceinline__ bool jax_keep(uint32_t j) {
  uint32_t o0, o1;
  threefry(0u, j, o0, o1);
  uint32_t bits = o0 ^ o1;
  float u = __builtin_bit_cast(float, (bits >> 9) | 0x3f800000u) - 1.0f;
  return u < 0.9f;
}

// 128x128 output tile, 4 waves (each 64x64), K in {64,128}.
// LDS: row-major [row][K] bf16, 16B granules XOR-swizzled by (row & GM)
// -> conflict-free ds_read_b128 fragment loads, fits 64KiB, no padding.
// A-frag: m = lane&15, k = (lane>>4)*8 + j ; B-frag: n = lane&15, same k.
// C/D:    col = lane&15, row = (lane>>4)*4 + reg   [m89/m91-verified mapping]
template <int K, int GM>
__device__ __forceinline__ void mfma_tile(const u16* sA, const u16* sBT,
                                          int t, f32x4 (&c)[4][4]) {
  const int lane = t & 63, w = t >> 6;
  const int wr = (w & 1) << 6, wc = (w >> 1) << 6;
  const int quad = lane >> 4, lr = lane & 15;
#pragma unroll
  for (int i = 0; i < 4; ++i)
#pragma unroll
    for (int j = 0; j < 4; ++j) { f32x4 z = {0.f, 0.f, 0.f, 0.f}; c[i][j] = z; }
#pragma unroll
  for (int ks = 0; ks < K; ks += 32) {
    const int kg = (ks >> 3) + quad;
    bf16x8 a[4], b[4];
#pragma unroll
    for (int i = 0; i < 4; ++i) {
      int row = wr + (i << 4) + lr;
      a[i] = *(const bf16x8*)&sA[row * K + ((kg ^ (row & GM)) << 3)];
    }
#pragma unroll
    for (int j = 0; j < 4; ++j) {
      int row = wc + (j << 4) + lr;
      b[j] = *(const bf16x8*)&sBT[row * K + ((kg ^ (row & GM)) << 3)];
    }
#pragma unroll
    for (int i = 0; i < 4; ++i)
#pragma unroll
      for (int j = 0; j < 4; ++j)
        c[i][j] = __builtin_amdgcn_mfma_f32_16x16x32_bf16(a[i], b[j], c[i][j], 0, 0, 0);
  }
}

// K1: Hp = bf16(hidden @ W_msg[0:128,:] + b_msg)   [N,128] bf16
__global__ __launch_bounds__(256) void k_hp(const float* __restrict__ hidden,
                                            const float* __restrict__ Wmsg,
                                            const float* __restrict__ bmsg,
                                            u16* __restrict__ Hp) {
  __shared__ u16 sA[128 * 128];
  __shared__ u16 sBT[128 * 128];
  const int t = threadIdx.x;
  const int row0 = blockIdx.x << 7;
#pragma unroll
  for (int it = 0; it < 16; ++it) {
    int li = t + (it << 8);
    int row = li >> 5, c4 = li & 31;
    int n = row0 + row;
    f32x4 v = {0.f, 0.f, 0.f, 0.f};
    if (n < NN) v = *(const f32x4*)(hidden + ((size_t)n << 7) + (c4 << 2));
    u16x4 b = {f2b(v[0]), f2b(v[1]), f2b(v[2]), f2b(v[3])};
    *(u16x4*)&sA[(row << 7) + ((((c4 >> 1) ^ (row & 15)) << 3) + ((c4 & 1) << 2))] = b;
  }
#pragma unroll
  for (int it = 0; it < 64; ++it) {
    int li = t + (it << 8);
    int k = li >> 7, d = li & 127;
    sBT[(d << 7) + ((((k >> 3) ^ (d & 15)) << 3) + (k & 7))] = f2b(Wmsg[li]);
  }
  __syncthreads();
  f32x4 c[4][4];
  mfma_tile<128, 15>(sA, sBT, t, c);
  const int lane = t & 63, w = t >> 6;
  const int wr = (w & 1) << 6, wc = (w >> 1) << 6;
  const int quad = lane >> 4, lr = lane & 15;
#pragma unroll
  for (int j = 0; j < 4; ++j) {
    int d = wc + (j << 4) + lr;
    float bias = bmsg[d];
#pragma unroll
    for (int i = 0; i < 4; ++i) {
      int nb = row0 + wr + (i << 4) + (quad << 2);
#pragma unroll
      for (int r = 0; r < 4; ++r) {
        int n = nb + r;
        if (n < NN) Hp[((size_t)n << 7) + d] = f2b(c[i][j][r] + bias);
      }
    }
  }
}

// K2: P = [attr|time] @ W_msg[128:192,:]; msg = relu(P + Hp[src]); acc[dst] += msg
__global__ __launch_bounds__(256) void k_edge(const float* __restrict__ attr,
                                              const float* __restrict__ tim,
                                              const int* __restrict__ ei,
                                              const float* __restrict__ Wmsg,
                                              const u16* __restrict__ Hp,
                                              float* __restrict__ acc) {
  __shared__ union {
    struct { u16 A[128 * 64]; u16 BT[128 * 64]; } ab;
    float C[128 * 128];
  } lds;
  const int t = threadIdx.x;
  const int e0 = blockIdx.x << 7;
#pragma unroll
  for (int it = 0; it < 4; ++it) {
    int li = t + (it << 8);
    int row = li >> 3, c4 = li & 7;
    int e = e0 + row;
    f32x4 va = {0.f, 0.f, 0.f, 0.f}, vt = {0.f, 0.f, 0.f, 0.f};
    if (e < NE) {
      va = *(const f32x4*)(attr + ((size_t)e << 5) + (c4 << 2));
      vt = *(const f32x4*)(tim + ((size_t)e << 5) + (c4 << 2));
    }
    int g0 = c4 >> 1, h = (c4 & 1) << 2;
    u16x4 ba = {f2b(va[0]), f2b(va[1]), f2b(va[2]), f2b(va[3])};
    u16x4 bt = {f2b(vt[0]), f2b(vt[1]), f2b(vt[2]), f2b(vt[3])};
    *(u16x4*)&lds.ab.A[(row << 6) + (((g0 ^ (row & 7)) << 3) + h)] = ba;
    *(u16x4*)&lds.ab.A[(row << 6) + ((((g0 + 4) ^ (row & 7)) << 3) + h)] = bt;
  }
#pragma unroll
  for (int it = 0; it < 32; ++it) {
    int li = t + (it << 8);
    int k = li >> 7, d = li & 127;
    lds.ab.BT[(d << 6) + ((((k >> 3) ^ (d & 7)) << 3) + (k & 7))] = f2b(Wmsg[16384 + li]);
  }
  __syncthreads();
  f32x4 c[4][4];
  mfma_tile<64, 7>(lds.ab.A, lds.ab.BT, t, c);
  __syncthreads();
  {
    const int lane = t & 63, w = t >> 6;
    const int wr = (w & 1) << 6, wc = (w >> 1) << 6;
    const int quad = lane >> 4, lr = lane & 15;
#pragma unroll
    for (int i = 0; i < 4; ++i)
#pragma unroll
      for (int j = 0; j < 4; ++j)
#pragma unroll
        for (int r = 0; r < 4; ++r) {
          int row = wr + (i << 4) + (quad << 2) + r;
          int col = wc + (j << 4) + lr;
          lds.C[(row << 7) + ((((col >> 2) ^ (row & 31)) << 2) + (col & 3))] = c[i][j][r];
        }
  }
  __syncthreads();
  const int el = t >> 1, off = (t & 1) << 6;
  const int e = e0 + el;
  if (e < NE) {
    const int src = ei[e];
    const int dst = ei[NE + e];
    const u32x4* hp4 = (const u32x4*)(Hp + ((size_t)src << 7) + off);
    float* ap = acc + ((size_t)dst << 7) + off;
    for (int g = 0; g < 8; ++g) {
      u32x4 hv = hp4[g];
      int cb = off + (g << 3);
      f32x4 c0 = *(const f32x4*)&lds.C[(el << 7) + ((((cb >> 2) + 0) ^ (el & 31)) << 2)];
      f32x4 c1 = *(const f32x4*)&lds.C[(el << 7) + ((((cb >> 2) + 1) ^ (el & 31)) << 2)];
      float hf[8];
      hf[0] = b2f(hv[0] & 0xffffu); hf[1] = b2f(hv[0] >> 16);
      hf[2] = b2f(hv[1] & 0xffffu); hf[3] = b2f(hv[1] >> 16);
      hf[4] = b2f(hv[2] & 0xffffu); hf[5] = b2f(hv[2] >> 16);
      hf[6] = b2f(hv[3] & 0xffffu); hf[7] = b2f(hv[3] >> 16);
#pragma unroll
      for (int q = 0; q < 4; ++q) {
        float v0 = fmaxf(c0[q] + hf[q], 0.f);
        float v1 = fmaxf(c1[q] + hf[q + 4], 0.f);
        unsafeAtomicAdd(ap + (g << 3) + q, v0);
        unsafeAtomicAdd(ap + (g << 3) + 4 + q, v1);
      }
    }
  }
}

// K3 (in-place: accout holds scatter-sum on entry, final output on exit):
// out = dropout(relu(LN((acc+boundary) @ W_lin + b_lin)))
// Each block reads only its own 128 rows before writing them -> race-free.
__global__ __launch_bounds__(256) void k_out(float* accout,
                                             const float* __restrict__ bnd,
                                             const float* __restrict__ Wlin,
                                             const float* __restrict__ blin,
                                             const float* __restrict__ gam,
                                             const float* __restrict__ bet) {
  __shared__ union {
    struct { u16 A[128 * 128]; u16 BT[128 * 128]; } ab;
    float C[128 * 128];
  } lds;
  const int t = threadIdx.x;
  const int row0 = blockIdx.x << 7;
#pragma unroll
  for (int it = 0; it < 16; ++it) {
    int li = t + (it << 8);
    int row = li >> 5, c4 = li & 31;
    int n = row0 + row;
    f32x4 v = {0.f, 0.f, 0.f, 0.f};
    if (n < NN) {
      f32x4 a = *(const f32x4*)(accout + ((size_t)n << 7) + (c4 << 2));
      f32x4 b = *(const f32x4*)(bnd + ((size_t)n << 7) + (c4 << 2));
      v = a + b;
    }
    u16x4 bb = {f2b(v[0]), f2b(v[1]), f2b(v[2]), f2b(v[3])};
    *(u16x4*)&lds.ab.A[(row << 7) + ((((c4 >> 1) ^ (row & 15)) << 3) + ((c4 & 1) << 2))] = bb;
  }
#pragma unroll
  for (int it = 0; it < 64; ++it) {
    int li = t + (it << 8);
    int k = li >> 7, d = li & 127;
    lds.ab.BT[(d << 7) + ((((k >> 3) ^ (d & 15)) << 3) + (k & 7))] = f2b(Wlin[li]);
  }
  __syncthreads();
  f32x4 c[4][4];
  mfma_tile<128, 15>(lds.ab.A, lds.ab.BT, t, c);
  __syncthreads();
  {
    const int lane = t & 63, w = t >> 6;
    const int wr = (w & 1) << 6, wc = (w >> 1) << 6;
    const int quad = lane >> 4, lr = lane & 15;
#pragma unroll
    for (int i = 0; i < 4; ++i)
#pragma unroll
      for (int j = 0; j < 4; ++j)
#pragma unroll
        for (int r = 0; r < 4; ++r) {
          int row = wr + (i << 4) + (quad << 2) + r;
          int col = wc + (j << 4) + lr;
          lds.C[(row << 7) + ((((col >> 2) ^ (row & 31)) << 2) + (col & 3))] = c[i][j][r];
        }
  }
  __syncthreads();
  const int row = t >> 1, off = (t & 1) << 6;
  const int n = row0 + row;
  float s1 = 0.f, s2 = 0.f;
  if (n < NN) {
    for (int g = 0; g < 16; ++g) {
      int cb = off + (g << 2);
      f32x4 cv = *(const f32x4*)&lds.C[(row << 7) + (((cb >> 2) ^ (row & 31)) << 2)];
#pragma unroll
      for (int q = 0; q < 4; ++q) {
        float x = cv[q] + blin[cb + q];
        s1 += x; s2 += x * x;
      }
    }
  }
  s1 += __shfl_xor(s1, 1, 64);
  s2 += __shfl_xor(s2, 1, 64);
  if (n < NN) {
    const float mean = s1 * 0.0078125f;
    const float var = s2 * 0.0078125f - mean * mean;
    const float inv = 1.0f / sqrtf(var + 1e-5f);
    for (int g = 0; g < 16; ++g) {
      int cb = off + (g << 2);
      f32x4 cv = *(const f32x4*)&lds.C[(row << 7) + (((cb >> 2) ^ (row & 31)) << 2)];
#pragma unroll
      for (int q = 0; q < 4; ++q) {
        int d = cb + q;
        float x = cv[q] + blin[d];
        float y = (x - mean) * inv * gam[d] + bet[d];
        y = fmaxf(y, 0.f);
        uint32_t jj = ((uint32_t)n << 7) + (uint32_t)d;
        accout[((size_t)n << 7) + d] = jax_keep(jj) ? (y * (1.0f / 0.9f)) : 0.0f;
      }
    }
  }
}

extern "C" void kernel_launch(void* const* d_in, const int* in_sizes, int n_in,
                              void* d_out, int out_size, void* d_ws, size_t ws_size,
                              hipStream_t stream) {
  (void)in_sizes; (void)n_in; (void)out_size; (void)ws_size;
  const float* hidden = (const float*)d_in[0];
  const int*   ei     = (const int*)d_in[1];
  const float* attr   = (const float*)d_in[2];
  const float* tim    = (const float*)d_in[3];
  const float* bnd    = (const float*)d_in[4];
  const float* Wmsg   = (const float*)d_in[5];
  const float* bmsg   = (const float*)d_in[6];
  const float* Wlin   = (const float*)d_in[7];
  const float* blin   = (const float*)d_in[8];
  const float* gam    = (const float*)d_in[9];
  const float* bet    = (const float*)d_in[10];

  float* acc = (float*)d_out;        // [N,128] f32 scatter accumulator, in-place
  u16* Hp = (u16*)d_ws;              // [N,128] bf16

  hipMemsetAsync(acc, 0, (size_t)NN * 128 * 4, stream);
  k_hp<<<dim3((NN + 127) / 128), dim3(256), 0, stream>>>(hidden, Wmsg, bmsg, Hp);
  k_edge<<<dim3((NE + 127) / 128), dim3(256), 0, stream>>>(attr, tim, ei, Wmsg, Hp, acc);
  k_out<<<dim3((NN + 127) / 128), dim3(256), 0, stream>>>(acc, bnd, Wlin, blin, gam, bet);
}

// Round 3
// 456.855 us; speedup vs baseline: 7.6789x; 7.6789x over previous
//
#include <hip/hip_runtime.h>
#include <stdint.h>

#define NN 50000
#define NE 500000
#define SPB 126                   // slots (edges) per k_edge2 block; C[126][128] f32 = 63 KB LDS
#define NBLK_N ((NN + 255) / 256) // 196 blocks for node-array scans

typedef short bf16x8 __attribute__((ext_vector_type(8)));
typedef float f32x4 __attribute__((ext_vector_type(4)));
typedef unsigned short u16;
typedef unsigned short u16x4 __attribute__((ext_vector_type(4)));
typedef unsigned int u32x4 __attribute__((ext_vector_type(4)));

__device__ __forceinline__ u16 f2b(float x) {
  uint32_t u = __builtin_bit_cast(uint32_t, x);
  return (u16)((u + 0x7fffu + ((u >> 16) & 1u)) >> 16);
}
__device__ __forceinline__ float b2f(uint32_t lo16) {
  return __builtin_bit_cast(float, lo16 << 16);
}

// JAX threefry2x32, key = jax.random.key(42) -> (0, 42)
__device__ __forceinline__ void threefry(uint32_t x0, uint32_t x1,
                                         uint32_t& o0, uint32_t& o1) {
  const uint32_t k0 = 0u, k1 = 42u, k2 = 0u ^ 42u ^ 0x1BD11BDAu;
  x0 += k0; x1 += k1;
#define TFR(r) { x0 += x1; x1 = (x1 << r) | (x1 >> (32 - r)); x1 ^= x0; }
  TFR(13) TFR(15) TFR(26) TFR(6)
  x0 += k1; x1 += k2 + 1u;
  TFR(17) TFR(29) TFR(16) TFR(24)
  x0 += k2; x1 += k0 + 2u;
  TFR(13) TFR(15) TFR(26) TFR(6)
  x0 += k0; x1 += k1 + 3u;
  TFR(17) TFR(29) TFR(16) TFR(24)
  x0 += k1; x1 += k2 + 4u;
  TFR(13) TFR(15) TFR(26) TFR(6)
  x0 += k2; x1 += k0 + 5u;
#undef TFR
  o0 = x0; o1 = x1;
}

// JAX partitionable random_bits: bits(j) = o0^o1 of threefry(0, j)
__device__ __forceinline__ bool jax_keep(uint32_t j) {
  uint32_t o0, o1;
  threefry(0u, j, o0, o1);
  uint32_t bits = o0 ^ o1;
  float u = __builtin_bit_cast(float, (bits >> 9) | 0x3f800000u) - 1.0f;
  return u < 0.9f;
}

// 128x128 output tile, 4 waves (each 64x64), K in {64,128}.
// LDS: row-major [row][K] bf16, 16B granules XOR-swizzled by (row & GM).
// C/D: col = lane&15, row = (lane>>4)*4 + reg
template <int K, int GM>
__device__ __forceinline__ void mfma_tile(const u16* sA, const u16* sBT,
                                          int t, f32x4 (&c)[4][4]) {
  const int lane = t & 63, w = t >> 6;
  const int wr = (w & 1) << 6, wc = (w >> 1) << 6;
  const int quad = lane >> 4, lr = lane & 15;
#pragma unroll
  for (int i = 0; i < 4; ++i)
#pragma unroll
    for (int j = 0; j < 4; ++j) { f32x4 z = {0.f, 0.f, 0.f, 0.f}; c[i][j] = z; }
#pragma unroll
  for (int ks = 0; ks < K; ks += 32) {
    const int kg = (ks >> 3) + quad;
    bf16x8 a[4], b[4];
#pragma unroll
    for (int i = 0; i < 4; ++i) {
      int row = wr + (i << 4) + lr;
      a[i] = *(const bf16x8*)&sA[row * K + ((kg ^ (row & GM)) << 3)];
    }
#pragma unroll
    for (int j = 0; j < 4; ++j) {
      int row = wc + (j << 4) + lr;
      b[j] = *(const bf16x8*)&sBT[row * K + ((kg ^ (row & GM)) << 3)];
    }
#pragma unroll
    for (int i = 0; i < 4; ++i)
#pragma unroll
      for (int j = 0; j < 4; ++j)
        c[i][j] = __builtin_amdgcn_mfma_f32_16x16x32_bf16(a[i], b[j], c[i][j], 0, 0, 0);
  }
}

// ---- CSR build ----
__global__ __launch_bounds__(256) void k_deg(const int* __restrict__ ei,
                                             uint32_t* __restrict__ deg) {
  int i = blockIdx.x * 256 + threadIdx.x;
  if (i < NE) atomicAdd(&deg[ei[NE + i]], 1u);
}

__global__ __launch_bounds__(256) void k_scan1(const uint32_t* __restrict__ deg,
                                               uint32_t* __restrict__ ex,
                                               uint32_t* __restrict__ bsum) {
  __shared__ uint32_t s[256];
  int t = threadIdx.x;
  int i = blockIdx.x * 256 + t;
  uint32_t v = (i < NN) ? deg[i] : 0u;
  s[t] = v;
  __syncthreads();
#pragma unroll
  for (int off = 1; off < 256; off <<= 1) {
    uint32_t y = (t >= off) ? s[t - off] : 0u;
    __syncthreads();
    s[t] += y;
    __syncthreads();
  }
  if (i < NN) ex[i] = s[t] - v;
  if (t == 255) bsum[blockIdx.x] = s[255];
}

__global__ __launch_bounds__(256) void k_scan2(const uint32_t* __restrict__ bsum,
                                               uint32_t* __restrict__ boff) {
  __shared__ uint32_t s[256];
  int t = threadIdx.x;
  uint32_t v = (t < NBLK_N) ? bsum[t] : 0u;
  s[t] = v;
  __syncthreads();
#pragma unroll
  for (int off = 1; off < 256; off <<= 1) {
    uint32_t y = (t >= off) ? s[t - off] : 0u;
    __syncthreads();
    s[t] += y;
    __syncthreads();
  }
  boff[t] = s[t] - v;  // exclusive
}

__global__ __launch_bounds__(256) void k_scan3(const uint32_t* __restrict__ ex,
                                               const uint32_t* __restrict__ boff,
                                               uint32_t* __restrict__ cursor) {
  int i = blockIdx.x * 256 + threadIdx.x;
  if (i < NN) cursor[i] = ex[i] + boff[blockIdx.x];
}

__global__ __launch_bounds__(256) void k_perm(const int* __restrict__ ei,
                                              uint32_t* __restrict__ cursor,
                                              int* __restrict__ perm) {
  int i = blockIdx.x * 256 + threadIdx.x;
  if (i < NE) {
    uint32_t pos = atomicAdd(&cursor[ei[NE + i]], 1u);
    perm[pos] = i;
  }
}

// K1: Hp = bf16(hidden @ W_msg[0:128,:] + b_msg)   [N,128] bf16
__global__ __launch_bounds__(256) void k_hp(const float* __restrict__ hidden,
                                            const float* __restrict__ Wmsg,
                                            const float* __restrict__ bmsg,
                                            u16* __restrict__ Hp) {
  __shared__ u16 sA[128 * 128];
  __shared__ u16 sBT[128 * 128];
  const int t = threadIdx.x;
  const int row0 = blockIdx.x << 7;
#pragma unroll
  for (int it = 0; it < 16; ++it) {
    int li = t + (it << 8);
    int row = li >> 5, c4 = li & 31;
    int n = row0 + row;
    f32x4 v = {0.f, 0.f, 0.f, 0.f};
    if (n < NN) v = *(const f32x4*)(hidden + ((size_t)n << 7) + (c4 << 2));
    u16x4 b = {f2b(v[0]), f2b(v[1]), f2b(v[2]), f2b(v[3])};
    *(u16x4*)&sA[(row << 7) + ((((c4 >> 1) ^ (row & 15)) << 3) + ((c4 & 1) << 2))] = b;
  }
#pragma unroll
  for (int it = 0; it < 64; ++it) {
    int li = t + (it << 8);
    int k = li >> 7, d = li & 127;
    sBT[(d << 7) + ((((k >> 3) ^ (d & 15)) << 3) + (k & 7))] = f2b(Wmsg[li]);
  }
  __syncthreads();
  f32x4 c[4][4];
  mfma_tile<128, 15>(sA, sBT, t, c);
  const int lane = t & 63, w = t >> 6;
  const int wr = (w & 1) << 6, wc = (w >> 1) << 6;
  const int quad = lane >> 4, lr = lane & 15;
#pragma unroll
  for (int j = 0; j < 4; ++j) {
    int d = wc + (j << 4) + lr;
    float bias = bmsg[d];
#pragma unroll
    for (int i = 0; i < 4; ++i) {
      int nb = row0 + wr + (i << 4) + (quad << 2);
#pragma unroll
      for (int r = 0; r < 4; ++r) {
        int n = nb + r;
        if (n < NN) Hp[((size_t)n << 7) + d] = f2b(c[i][j][r] + bias);
      }
    }
  }
}

// K2: slots = dst-sorted edges. P = gather([attr|time], perm) @ Wc (MFMA);
// msg = relu(P + Hp[src]) in LDS (f32); segmented per-column reduction over
// dst runs; interior runs -> plain store, boundary runs -> atomic (~2/block).
__global__ __launch_bounds__(256) void k_edge2(const float* __restrict__ attr,
                                               const float* __restrict__ tim,
                                               const int* __restrict__ ei,
                                               const float* __restrict__ Wmsg,
                                               const int* __restrict__ perm,
                                               const u16* __restrict__ Hp,
                                               float* __restrict__ acc) {
  __shared__ union {
    struct { u16 A[128 * 64]; u16 BT[128 * 64]; } ab; // 32 KB
    float C[SPB * 128];                               // 63 KB
  } lds;
  __shared__ int sdst[128];
  const int t = threadIdx.x;
  const long e0 = (long)blockIdx.x * SPB;

  // A gather: 8 threads per slot row, f32x4 each from attr and tim
#pragma unroll
  for (int it = 0; it < 4; ++it) {
    int li = t + (it << 8);
    int row = li >> 3, c4 = li & 7;
    long sg = e0 + row;
    f32x4 va = {0.f, 0.f, 0.f, 0.f}, vt = {0.f, 0.f, 0.f, 0.f};
    if (row < SPB && sg < NE) {
      int e = perm[sg];
      va = *(const f32x4*)(attr + ((size_t)e << 5) + (c4 << 2));
      vt = *(const f32x4*)(tim + ((size_t)e << 5) + (c4 << 2));
    }
    int g0 = c4 >> 1, h = (c4 & 1) << 2;
    u16x4 ba = {f2b(va[0]), f2b(va[1]), f2b(va[2]), f2b(va[3])};
    u16x4 bt = {f2b(vt[0]), f2b(vt[1]), f2b(vt[2]), f2b(vt[3])};
    *(u16x4*)&lds.ab.A[(row << 6) + (((g0 ^ (row & 7)) << 3) + h)] = ba;
    *(u16x4*)&lds.ab.A[(row << 6) + ((((g0 + 4) ^ (row & 7)) << 3) + h)] = bt;
  }
#pragma unroll
  for (int it = 0; it < 32; ++it) {
    int li = t + (it << 8);
    int k = li >> 7, d = li & 127;
    lds.ab.BT[(d << 6) + ((((k >> 3) ^ (d & 7)) << 3) + (k & 7))] = f2b(Wmsg[16384 + li]);
  }

  // per-slot src/dst (2 threads per slot)
  const int s = t >> 1;
  const long sg1 = e0 + s;
  const bool v1 = (t < 2 * SPB) && (sg1 < NE);
  int src = 0, dstn = -1;
  if (v1) {
    int pe = perm[sg1];
    src = ei[pe];
    dstn = ei[NE + pe];
  }
  __syncthreads();
  f32x4 c[4][4];
  mfma_tile<64, 7>(lds.ab.A, lds.ab.BT, t, c);
  __syncthreads();
  {
    const int lane = t & 63, w = t >> 6;
    const int wr = (w & 1) << 6, wc = (w >> 1) << 6;
    const int quad = lane >> 4, lr = lane & 15;
#pragma unroll
    for (int i = 0; i < 4; ++i)
#pragma unroll
      for (int j = 0; j < 4; ++j)
#pragma unroll
        for (int r = 0; r < 4; ++r) {
          int row = wr + (i << 4) + (quad << 2) + r;
          int col = wc + (j << 4) + lr;
          if (row < SPB)
            lds.C[(row << 7) + ((((col >> 2) ^ (row & 31)) << 2) + (col & 3))] = c[i][j][r];
        }
  }
  if ((t & 1) == 0 && t < 2 * SPB) sdst[s] = v1 ? dstn : -1;
  __syncthreads();
  // stage 1: msg = relu(P + Hp[src]) in place (f32), 2 threads per slot
  if (v1) {
    const int off = (t & 1) << 6;
    const u32x4* hp4 = (const u32x4*)(Hp + ((size_t)src << 7) + off);
#pragma unroll
    for (int g = 0; g < 8; ++g) {
      u32x4 hv = hp4[g];
      int cb = off + (g << 3);
      float* p0 = &lds.C[(s << 7) + ((((cb >> 2) + 0) ^ (s & 31)) << 2)];
      float* p1 = &lds.C[(s << 7) + ((((cb >> 2) + 1) ^ (s & 31)) << 2)];
      f32x4 c0 = *(const f32x4*)p0, c1 = *(const f32x4*)p1;
      float hf[8];
      hf[0] = b2f(hv[0] & 0xffffu); hf[1] = b2f(hv[0] >> 16);
      hf[2] = b2f(hv[1] & 0xffffu); hf[3] = b2f(hv[1] >> 16);
      hf[4] = b2f(hv[2] & 0xffffu); hf[5] = b2f(hv[2] >> 16);
      hf[6] = b2f(hv[3] & 0xffffu); hf[7] = b2f(hv[3] >> 16);
#pragma unroll
      for (int q = 0; q < 4; ++q) {
        c0[q] = fmaxf(c0[q] + hf[q], 0.f);
        c1[q] = fmaxf(c1[q] + hf[q + 4], 0.f);
      }
      *(f32x4*)p0 = c0;
      *(f32x4*)p1 = c1;
    }
  }
  __syncthreads();
  // stage 2: per-column segmented reduction (dst is wave-uniform -> no divergence)
  if (t < 128) {
    const int col = t;
    int cur = sdst[0];
    float sum = 0.f;
    int runstart = 0;
#pragma unroll 2
    for (int ss = 0; ss < SPB; ++ss) {
      int d = sdst[ss];
      if (d != cur) {
        if (cur >= 0) {
          float* p = acc + ((size_t)cur << 7) + col;
          if (runstart == 0) unsafeAtomicAdd(p, sum);
          else *p = sum;
        }
        cur = d; sum = 0.f; runstart = ss;
      }
      sum += lds.C[(ss << 7) + ((((col >> 2) ^ (ss & 31)) << 2) + (col & 3))];
    }
    if (cur >= 0) {
      float* p = acc + ((size_t)cur << 7) + col;
      unsafeAtomicAdd(p, sum);  // run touches block end (or start) -> atomic
    }
  }
}

// K3 (in-place): out = dropout(relu(LN((acc+boundary) @ W_lin + b_lin)))
__global__ __launch_bounds__(256) void k_out(float* accout,
                                             const float* __restrict__ bnd,
                                             const float* __restrict__ Wlin,
                                             const float* __restrict__ blin,
                                             const float* __restrict__ gam,
                                             const float* __restrict__ bet) {
  __shared__ union {
    struct { u16 A[128 * 128]; u16 BT[128 * 128]; } ab;
    float C[128 * 128];
  } lds;
  const int t = threadIdx.x;
  const int row0 = blockIdx.x << 7;
#pragma unroll
  for (int it = 0; it < 16; ++it) {
    int li = t + (it << 8);
    int row = li >> 5, c4 = li & 31;
    int n = row0 + row;
    f32x4 v = {0.f, 0.f, 0.f, 0.f};
    if (n < NN) {
      f32x4 a = *(const f32x4*)(accout + ((size_t)n << 7) + (c4 << 2));
      f32x4 b = *(const f32x4*)(bnd + ((size_t)n << 7) + (c4 << 2));
      v = a + b;
    }
    u16x4 bb = {f2b(v[0]), f2b(v[1]), f2b(v[2]), f2b(v[3])};
    *(u16x4*)&lds.ab.A[(row << 7) + ((((c4 >> 1) ^ (row & 15)) << 3) + ((c4 & 1) << 2))] = bb;
  }
#pragma unroll
  for (int it = 0; it < 64; ++it) {
    int li = t + (it << 8);
    int k = li >> 7, d = li & 127;
    lds.ab.BT[(d << 7) + ((((k >> 3) ^ (d & 15)) << 3) + (k & 7))] = f2b(Wlin[li]);
  }
  __syncthreads();
  f32x4 c[4][4];
  mfma_tile<128, 15>(lds.ab.A, lds.ab.BT, t, c);
  __syncthreads();
  {
    const int lane = t & 63, w = t >> 6;
    const int wr = (w & 1) << 6, wc = (w >> 1) << 6;
    const int quad = lane >> 4, lr = lane & 15;
#pragma unroll
    for (int i = 0; i < 4; ++i)
#pragma unroll
      for (int j = 0; j < 4; ++j)
#pragma unroll
        for (int r = 0; r < 4; ++r) {
          int row = wr + (i << 4) + (quad << 2) + r;
          int col = wc + (j << 4) + lr;
          lds.C[(row << 7) + ((((col >> 2) ^ (row & 31)) << 2) + (col & 3))] = c[i][j][r];
        }
  }
  __syncthreads();
  const int row = t >> 1, off = (t & 1) << 6;
  const int n = row0 + row;
  float s1 = 0.f, s2 = 0.f;
  if (n < NN) {
    for (int g = 0; g < 16; ++g) {
      int cb = off + (g << 2);
      f32x4 cv = *(const f32x4*)&lds.C[(row << 7) + (((cb >> 2) ^ (row & 31)) << 2)];
#pragma unroll
      for (int q = 0; q < 4; ++q) {
        float x = cv[q] + blin[cb + q];
        s1 += x; s2 += x * x;
      }
    }
  }
  s1 += __shfl_xor(s1, 1, 64);
  s2 += __shfl_xor(s2, 1, 64);
  if (n < NN) {
    const float mean = s1 * 0.0078125f;
    const float var = s2 * 0.0078125f - mean * mean;
    const float inv = 1.0f / sqrtf(var + 1e-5f);
    for (int g = 0; g < 16; ++g) {
      int cb = off + (g << 2);
      f32x4 cv = *(const f32x4*)&lds.C[(row << 7) + (((cb >> 2) ^ (row & 31)) << 2)];
#pragma unroll
      for (int q = 0; q < 4; ++q) {
        int d = cb + q;
        float x = cv[q] + blin[d];
        float y = (x - mean) * inv * gam[d] + bet[d];
        y = fmaxf(y, 0.f);
        uint32_t jj = ((uint32_t)n << 7) + (uint32_t)d;
        accout[((size_t)n << 7) + d] = jax_keep(jj) ? (y * (1.0f / 0.9f)) : 0.0f;
      }
    }
  }
}

extern "C" void kernel_launch(void* const* d_in, const int* in_sizes, int n_in,
                              void* d_out, int out_size, void* d_ws, size_t ws_size,
                              hipStream_t stream) {
  (void)in_sizes; (void)n_in; (void)out_size; (void)ws_size;
  const float* hidden = (const float*)d_in[0];
  const int*   ei     = (const int*)d_in[1];
  const float* attr   = (const float*)d_in[2];
  const float* tim    = (const float*)d_in[3];
  const float* bnd    = (const float*)d_in[4];
  const float* Wmsg   = (const float*)d_in[5];
  const float* bmsg   = (const float*)d_in[6];
  const float* Wlin   = (const float*)d_in[7];
  const float* blin   = (const float*)d_in[8];
  const float* gam    = (const float*)d_in[9];
  const float* bet    = (const float*)d_in[10];

  float* acc = (float*)d_out;  // [N,128] f32 accumulator, finalized in-place by k_out

  char* ws = (char*)d_ws;
  u16*      Hp     = (u16*)(ws + 0);              // 12,800,000 B
  uint32_t* deg    = (uint32_t*)(ws + 12800000);  //    200,000 B
  uint32_t* ex     = (uint32_t*)(ws + 13000000);  //    200,000 B
  uint32_t* bsum   = (uint32_t*)(ws + 13200000);  //      1,024 B
  uint32_t* boff   = (uint32_t*)(ws + 13201024);  //      1,024 B
  uint32_t* cursor = (uint32_t*)(ws + 13202048);  //    200,000 B
  int*      perm   = (int*)(ws + 13402048);       //  2,000,000 B

  hipMemsetAsync(deg, 0, (size_t)NN * 4, stream);
  hipMemsetAsync(acc, 0, (size_t)NN * 128 * 4, stream);

  k_deg  <<<dim3((NE + 255) / 256), dim3(256), 0, stream>>>(ei, deg);
  k_scan1<<<dim3(NBLK_N), dim3(256), 0, stream>>>(deg, ex, bsum);
  k_scan2<<<dim3(1), dim3(256), 0, stream>>>(bsum, boff);
  k_scan3<<<dim3(NBLK_N), dim3(256), 0, stream>>>(ex, boff, cursor);
  k_perm <<<dim3((NE + 255) / 256), dim3(256), 0, stream>>>(ei, cursor, perm);
  k_hp   <<<dim3((NN + 127) / 128), dim3(256), 0, stream>>>(hidden, Wmsg, bmsg, Hp);
  k_edge2<<<dim3((NE + SPB - 1) / SPB), dim3(256), 0, stream>>>(attr, tim, ei, Wmsg, perm, Hp, acc);
  k_out  <<<dim3((NN + 127) / 128), dim3(256), 0, stream>>>(acc, bnd, Wlin, blin, gam, bet);
}